// Round 1
// baseline (267.100 us; speedup 1.0000x reference)
//
#include <hip/hip_runtime.h>
#include <cstdint>
#include <cstddef>

typedef __bf16 bf16x8 __attribute__((ext_vector_type(8)));
typedef float  f32x4  __attribute__((ext_vector_type(4)));

#define QMAX 7.0f
#define SCALE_MIN 2e-16f

// ---------------------------------------------------------------------------
// Kernel 1: per-output-channel fake-quant of w [256,256,3,3] -> bf16 wq[tap][o][c]
// ---------------------------------------------------------------------------
__global__ __launch_bounds__(256) void quant_w_kernel(const float* __restrict__ w,
                                                      __bf16* __restrict__ wq) {
    const int o = blockIdx.x;          // 256 blocks
    const int t = threadIdx.x;         // 256 threads
    const float* wo = w + (size_t)o * 2304;

    float vals[9];
    float m = 0.f;
    #pragma unroll
    for (int i = 0; i < 9; ++i) {
        float v = wo[t + i * 256];
        vals[i] = v;
        m = fmaxf(m, fabsf(v));
    }
    // wave (64) reduce then cross-wave via LDS
    #pragma unroll
    for (int off = 32; off >= 1; off >>= 1) m = fmaxf(m, __shfl_down(m, off));
    __shared__ float red[4];
    __shared__ float s_scale;
    if ((t & 63) == 0) red[t >> 6] = m;
    __syncthreads();
    if (t == 0) {
        float am = fmaxf(fmaxf(red[0], red[1]), fmaxf(red[2], red[3]));
        s_scale = fmaxf(am / QMAX, SCALE_MIN);
    }
    __syncthreads();
    const float scale = s_scale;

    #pragma unroll
    for (int i = 0; i < 9; ++i) {
        int idx = t + i * 256;           // = c*9 + tap
        int c = idx / 9;
        int tap = idx - c * 9;
        float q = rintf(vals[i] / scale);          // round-half-even, matches jnp.round
        q = fminf(QMAX, fmaxf(-QMAX, q));
        wq[(size_t)tap * 65536 + (size_t)o * 256 + c] = (__bf16)(q * scale);
    }
}

// ---------------------------------------------------------------------------
// Kernel 2: x NCHW fp32 [32,256,56,56] -> padded NHWC bf16 [32][58][58][256]
// (border already zeroed by memset). 32x32 transpose tiles through LDS.
// ---------------------------------------------------------------------------
__global__ __launch_bounds__(256) void convert_x_kernel(const float* __restrict__ x,
                                                        __bf16* __restrict__ xpad) {
    __shared__ float tile[32][33];
    const int n  = blockIdx.z;
    const int c0 = blockIdx.y * 32;
    const int p0 = blockIdx.x * 32;     // 3136/32 = 98 exact
    const int tx = threadIdx.x & 31;
    const int ty = threadIdx.x >> 5;    // 0..7

    #pragma unroll
    for (int r = 0; r < 4; ++r) {
        int c = c0 + ty + r * 8;
        tile[ty + r * 8][tx] = x[((size_t)(n * 256 + c)) * 3136 + p0 + tx];
    }
    __syncthreads();
    #pragma unroll
    for (int r = 0; r < 4; ++r) {
        int p = p0 + ty + r * 8;
        int h = p / 56, wcol = p - h * 56;
        xpad[(((size_t)n * 58 + h + 1) * 58 + (wcol + 1)) * 256 + c0 + tx] =
            (__bf16)tile[tx][ty + r * 8];
    }
}

// ---------------------------------------------------------------------------
// Kernel 3: implicit-GEMM conv. Tile: 128 o x 128 pos, 4 waves, BK=32.
// A = wq[tap][o][c] (M=o), B = xpad patches (N=pos), K = 9 taps x 256 c.
// ---------------------------------------------------------------------------
__device__ __forceinline__ void gload_lds16(const void* g, void* l) {
    __builtin_amdgcn_global_load_lds((const __attribute__((address_space(1))) void*)g,
                                     (__attribute__((address_space(3))) void*)l,
                                     16, 0, 0);
}

__global__ __launch_bounds__(256) void conv_mfma_kernel(const __bf16* __restrict__ xpad,
                                                        const __bf16* __restrict__ wq,
                                                        float* __restrict__ out) {
    __shared__ __align__(16) char Ash[128 * 32 * 2];   // [o][k] 8 KB
    __shared__ __align__(16) char Bsh[128 * 32 * 2];   // [pos][k] 8 KB

    const int tid  = threadIdx.x;
    const int wv   = tid >> 6;
    const int lane = tid & 63;
    const int bp   = blockIdx.x;            // 0..799 (32 images x 25 tiles)
    const int n    = bp / 25;
    const int p0   = (bp - n * 25) * 128;
    const int o0   = blockIdx.y * 128;

    const int chunk = lane & 3;             // 16B chunk within 64B k-row

    // per-lane global base addresses for the two staging issues per tile
    const __bf16* bbase[2];
    const __bf16* abase[2];
    #pragma unroll
    for (int i = 0; i < 2; ++i) {
        int pos_local = wv * 32 + i * 16 + (lane >> 2);
        int p = p0 + pos_local;
        if (p > 3135) p = 3135;             // tail clamp (stores masked later)
        int h = p / 56, wcol = p - h * 56;
        bbase[i] = xpad + (((size_t)n * 58 + h) * 58 + wcol) * 256 + chunk * 8;
        int o_local = wv * 32 + i * 16 + (lane >> 2);
        abase[i] = wq + (size_t)(o0 + o_local) * 256 + chunk * 8;
    }

    const int wr = wv >> 1;   // o half (64)
    const int wc = wv & 1;    // pos half (64)

    // fragment LDS byte offsets: row*64 + (lane>>4)*16, row stride 64B
    const int a_row0 = wr * 64 + (lane & 15);
    const int b_row0 = wc * 64 + (lane & 15);
    const int kofs   = (lane >> 4) * 16;

    f32x4 acc[4][4];
    #pragma unroll
    for (int m = 0; m < 4; ++m)
        #pragma unroll
        for (int nf = 0; nf < 4; ++nf)
            acc[m][nf] = (f32x4){0.f, 0.f, 0.f, 0.f};

    for (int kk = 0; kk < 72; ++kk) {
        const int tap = kk >> 3;            // 0..8
        const int c0  = (kk & 7) * 32;
        const int kh  = tap / 3;
        const int kw  = tap - kh * 3;
        const size_t bstep = ((size_t)(kh * 58 + kw)) * 256 + c0;   // elements
        const size_t astep = (size_t)tap * 65536 + c0;

        #pragma unroll
        for (int i = 0; i < 2; ++i) {
            gload_lds16(bbase[i] + bstep, Bsh + (wv * 32 + i * 16) * 64);
            gload_lds16(abase[i] + astep, Ash + (wv * 32 + i * 16) * 64);
        }
        __syncthreads();                    // drains vmcnt before barrier

        bf16x8 a[4], b[4];
        #pragma unroll
        for (int m = 0; m < 4; ++m)
            a[m] = *(const bf16x8*)(Ash + (a_row0 + m * 16) * 64 + kofs);
        #pragma unroll
        for (int nf = 0; nf < 4; ++nf)
            b[nf] = *(const bf16x8*)(Bsh + (b_row0 + nf * 16) * 64 + kofs);

        #pragma unroll
        for (int m = 0; m < 4; ++m)
            #pragma unroll
            for (int nf = 0; nf < 4; ++nf)
                acc[m][nf] = __builtin_amdgcn_mfma_f32_16x16x32_bf16(a[m], b[nf], acc[m][nf], 0, 0, 0);

        __syncthreads();                    // protect LDS before next stage
    }

    // epilogue: D row = o = 4*(lane>>4)+reg (within 16), D col = pos = lane&15
    #pragma unroll
    for (int m = 0; m < 4; ++m) {
        const int obase = o0 + wr * 64 + m * 16 + (lane >> 4) * 4;
        #pragma unroll
        for (int nf = 0; nf < 4; ++nf) {
            const int p = p0 + wc * 64 + nf * 16 + (lane & 15);
            if (p < 3136) {
                #pragma unroll
                for (int r = 0; r < 4; ++r)
                    out[((size_t)(n * 256 + obase + r)) * 3136 + p] = acc[m][nf][r];
            }
        }
    }
}

// ---------------------------------------------------------------------------
// Fallback: naive direct conv (only if ws_size too small). Correct but slow.
// ---------------------------------------------------------------------------
__global__ __launch_bounds__(256) void conv_naive_kernel(const float* __restrict__ x,
                                                         const float* __restrict__ w,
                                                         float* __restrict__ out) {
    const int n = blockIdx.z;
    const int o = blockIdx.y;
    const int strip = blockIdx.x;
    __shared__ float wqs[2304];
    __shared__ float red[4];
    __shared__ float s_scale;
    const float* wo = w + (size_t)o * 2304;
    float m = 0.f;
    for (int i = threadIdx.x; i < 2304; i += 256) m = fmaxf(m, fabsf(wo[i]));
    #pragma unroll
    for (int off = 32; off >= 1; off >>= 1) m = fmaxf(m, __shfl_down(m, off));
    if ((threadIdx.x & 63) == 0) red[threadIdx.x >> 6] = m;
    __syncthreads();
    if (threadIdx.x == 0) {
        float am = fmaxf(fmaxf(red[0], red[1]), fmaxf(red[2], red[3]));
        s_scale = fmaxf(am / QMAX, SCALE_MIN);
    }
    __syncthreads();
    const float scale = s_scale;
    for (int i = threadIdx.x; i < 2304; i += 256) {
        float q = rintf(wo[i] / scale);
        q = fminf(QMAX, fmaxf(-QMAX, q));
        wqs[i] = q * scale;
    }
    __syncthreads();
    int p = strip * 256 + threadIdx.x;
    if (p >= 3136) return;
    int h = p / 56, wcol = p - h * 56;
    float acc = 0.f;
    for (int c = 0; c < 256; ++c) {
        const float* xc = x + ((size_t)(n * 256 + c)) * 3136;
        const float* wk = wqs + c * 9;
        #pragma unroll
        for (int kh = 0; kh < 3; ++kh) {
            int hh = h + kh - 1;
            if (hh < 0 || hh > 55) continue;
            #pragma unroll
            for (int kw = 0; kw < 3; ++kw) {
                int ww2 = wcol + kw - 1;
                if (ww2 < 0 || ww2 > 55) continue;
                acc += xc[hh * 56 + ww2] * wk[kh * 3 + kw];
            }
        }
    }
    out[((size_t)(n * 256 + o)) * 3136 + p] = acc;
}

// ---------------------------------------------------------------------------
extern "C" void kernel_launch(void* const* d_in, const int* in_sizes, int n_in,
                              void* d_out, int out_size, void* d_ws, size_t ws_size,
                              hipStream_t stream) {
    const float* x = (const float*)d_in[0];
    const float* w = (const float*)d_in[1];
    float* out = (float*)d_out;

    const size_t WQ_BYTES   = 9ull * 256 * 256 * 2;            // 1,179,648
    const size_t XPAD_OFF   = WQ_BYTES;                        // 16B aligned
    const size_t XPAD_BYTES = 32ull * 58 * 58 * 256 * 2;       // 55,083,008

    if (ws_size >= XPAD_OFF + XPAD_BYTES) {
        __bf16* wq   = (__bf16*)d_ws;
        __bf16* xpad = (__bf16*)((char*)d_ws + XPAD_OFF);
        hipMemsetAsync(xpad, 0, XPAD_BYTES, stream);           // zero padding halo
        quant_w_kernel<<<256, 256, 0, stream>>>(w, wq);
        convert_x_kernel<<<dim3(98, 8, 32), 256, 0, stream>>>(x, xpad);
        conv_mfma_kernel<<<dim3(800, 2), 256, 0, stream>>>(xpad, wq, out);
    } else {
        conv_naive_kernel<<<dim3(13, 256, 32), 256, 0, stream>>>(x, w, out);
    }
}

// Round 2
// 191.829 us; speedup vs baseline: 1.3924x; 1.3924x over previous
//
#include <hip/hip_runtime.h>
#include <cstdint>
#include <cstddef>

typedef __bf16 bf16x8 __attribute__((ext_vector_type(8)));
typedef float  f32x4  __attribute__((ext_vector_type(4)));
typedef int    i32x4  __attribute__((ext_vector_type(4)));

#define QMAX 7.0f
#define SCALE_MIN 2e-16f

// ---------------------------------------------------------------------------
// Kernel 1: per-output-channel fake-quant of w [256,256,3,3] -> bf16 wq[tap][o][c]
// ---------------------------------------------------------------------------
__global__ __launch_bounds__(256) void quant_w_kernel(const float* __restrict__ w,
                                                      __bf16* __restrict__ wq) {
    const int o = blockIdx.x;          // 256 blocks
    const int t = threadIdx.x;         // 256 threads
    const float* wo = w + (size_t)o * 2304;

    float vals[9];
    float m = 0.f;
    #pragma unroll
    for (int i = 0; i < 9; ++i) {
        float v = wo[t + i * 256];
        vals[i] = v;
        m = fmaxf(m, fabsf(v));
    }
    #pragma unroll
    for (int off = 32; off >= 1; off >>= 1) m = fmaxf(m, __shfl_down(m, off));
    __shared__ float red[4];
    __shared__ float s_scale;
    if ((t & 63) == 0) red[t >> 6] = m;
    __syncthreads();
    if (t == 0) {
        float am = fmaxf(fmaxf(red[0], red[1]), fmaxf(red[2], red[3]));
        s_scale = fmaxf(am / QMAX, SCALE_MIN);
    }
    __syncthreads();
    const float scale = s_scale;

    #pragma unroll
    for (int i = 0; i < 9; ++i) {
        int idx = t + i * 256;           // = c*9 + tap
        int c = idx / 9;
        int tap = idx - c * 9;
        float q = rintf(vals[i] / scale);          // round-half-even, matches jnp.round
        q = fminf(QMAX, fmaxf(-QMAX, q));
        wq[(size_t)tap * 65536 + (size_t)o * 256 + c] = (__bf16)(q * scale);
    }
}

// ---------------------------------------------------------------------------
// Kernel 2: x NCHW fp32 [32,256,56,56] -> padded NHWC bf16 [32][58][58][256]
// interior cells only; halo zeroed by zero_halo_kernel.
// ---------------------------------------------------------------------------
__global__ __launch_bounds__(256) void convert_x_kernel(const float* __restrict__ x,
                                                        __bf16* __restrict__ xpad) {
    __shared__ float tile[32][33];
    const int n  = blockIdx.z;
    const int c0 = blockIdx.y * 32;
    const int p0 = blockIdx.x * 32;     // 3136/32 = 98 exact
    const int tx = threadIdx.x & 31;
    const int ty = threadIdx.x >> 5;    // 0..7

    #pragma unroll
    for (int r = 0; r < 4; ++r) {
        int c = c0 + ty + r * 8;
        tile[ty + r * 8][tx] = x[((size_t)(n * 256 + c)) * 3136 + p0 + tx];
    }
    __syncthreads();
    #pragma unroll
    for (int r = 0; r < 4; ++r) {
        int p = p0 + ty + r * 8;
        int h = p / 56, wcol = p - h * 56;
        xpad[(((size_t)n * 58 + h + 1) * 58 + (wcol + 1)) * 256 + c0 + tx] =
            (__bf16)tile[tx][ty + r * 8];
    }
}

// ---------------------------------------------------------------------------
// Kernel 2b: zero the 1-cell halo of xpad. 228 border cells per image,
// 256 bf16 each -> 32 threads x 16B per cell. 32*228*32 = 233472 threads.
// ---------------------------------------------------------------------------
__global__ __launch_bounds__(256) void zero_halo_kernel(__bf16* __restrict__ xpad) {
    const int t = blockIdx.x * 256 + threadIdx.x;
    const int cvec = t & 31;
    const int r    = t >> 5;            // n*228 + pos
    const int n    = r / 228;
    const int pos  = r - n * 228;
    if (n >= 32) return;
    int h, wcol;
    if      (pos < 58)  { h = 0;          wcol = pos; }
    else if (pos < 116) { h = 57;         wcol = pos - 58; }
    else if (pos < 172) { h = pos - 115;  wcol = 0; }    // 1..56
    else                { h = pos - 171;  wcol = 57; }   // 1..56
    i32x4* dst = (i32x4*)(xpad + (((size_t)n * 58 + h) * 58 + wcol) * 256);
    dst[cvec] = (i32x4){0, 0, 0, 0};
}

// ---------------------------------------------------------------------------
// Kernel 3: implicit-GEMM conv. Tile: 128 o x 128 pos, 4 waves, BK=64.
// A = wq[tap][o][c] (M=o), B = xpad patches (N=pos), K = 9 taps x 4 x 64c.
// LDS rows are 128B (64 bf16); 16B chunks XOR-swizzled by (row&7) with the
// swizzle pre-applied on the GLOBAL source address (rule: both-sides, since
// global_load_lds writes linearly).
// ---------------------------------------------------------------------------
__device__ __forceinline__ void gload_lds16(const void* g, void* l) {
    __builtin_amdgcn_global_load_lds((const __attribute__((address_space(1))) void*)g,
                                     (__attribute__((address_space(3))) void*)l,
                                     16, 0, 0);
}

__global__ __launch_bounds__(256) void conv_mfma_kernel(const __bf16* __restrict__ xpad,
                                                        const __bf16* __restrict__ wq,
                                                        float* __restrict__ out) {
    __shared__ __align__(16) char Ash[128 * 128];   // [o row][128B] 16 KB
    __shared__ __align__(16) char Bsh[128 * 128];   // [pos row][128B] 16 KB

    const int tid  = threadIdx.x;
    const int wv   = tid >> 6;
    const int lane = tid & 63;
    const int bp   = blockIdx.x;            // 0..799 (32 images x 25 tiles)
    const int n    = bp / 25;
    const int p0   = (bp - n * 25) * 128;
    const int o0   = blockIdx.y * 128;

    // staging coords: per wave-issue j, rows [wv*8 + j*32, +8); lane>>3 = row
    // within group (== row&7), lane&7 = dest chunk. Source chunk pre-swizzled.
    const int srow   = wv * 8 + (lane >> 3);
    const int schunk = (lane & 7) ^ (lane >> 3);     // = destchunk ^ (row&7)
    const int selem  = schunk * 8;                   // bf16 elements

    const __bf16* pA = wq + (size_t)(o0 + srow) * 256 + selem;
    const __bf16* pB[4];
    #pragma unroll
    for (int j = 0; j < 4; ++j) {
        int p = p0 + srow + j * 32;
        if (p > 3135) p = 3135;             // tail clamp (stores masked later)
        int h = p / 56, wcol = p - h * 56;
        pB[j] = xpad + (((size_t)n * 58 + h) * 58 + wcol) * 256 + selem;
    }

    const int wr = wv >> 1;   // o half (64)
    const int wc = wv & 1;    // pos half (64)

    // fragment read: row = base + (lane&15), logical chunk s*4+(lane>>4),
    // stored at chunk ^ (row&7) = chunk ^ (lane&7).
    const int a_rowbyte = (wr * 64 + (lane & 15)) * 128;
    const int b_rowbyte = (wc * 64 + (lane & 15)) * 128;
    int kx[2];
    #pragma unroll
    for (int s = 0; s < 2; ++s)
        kx[s] = ((s * 4 + (lane >> 4)) ^ (lane & 7)) * 16;

    f32x4 acc[4][4];
    #pragma unroll
    for (int m = 0; m < 4; ++m)
        #pragma unroll
        for (int nf = 0; nf < 4; ++nf)
            acc[m][nf] = (f32x4){0.f, 0.f, 0.f, 0.f};

    for (int tap = 0; tap < 9; ++tap) {
        const int kh = tap / 3, kw = tap - kh * 3;          // uniform, SALU
        const size_t aoff0 = (size_t)tap * 65536;
        const size_t boff0 = (size_t)(kh * 58 + kw) * 256;
        #pragma unroll
        for (int cc = 0; cc < 4; ++cc) {
            const size_t aoff = aoff0 + cc * 64;
            const size_t boff = boff0 + cc * 64;
            #pragma unroll
            for (int j = 0; j < 4; ++j) {
                gload_lds16(pB[j] + boff, Bsh + (wv * 8 + j * 32) * 128);
                gload_lds16(pA + j * 8192 + aoff, Ash + (wv * 8 + j * 32) * 128);
            }
            __syncthreads();                // drains vmcnt: tiles ready

            #pragma unroll
            for (int s = 0; s < 2; ++s) {
                bf16x8 a[4], b[4];
                #pragma unroll
                for (int m = 0; m < 4; ++m)
                    a[m] = *(const bf16x8*)(Ash + a_rowbyte + m * 2048 + kx[s]);
                #pragma unroll
                for (int nf = 0; nf < 4; ++nf)
                    b[nf] = *(const bf16x8*)(Bsh + b_rowbyte + nf * 2048 + kx[s]);
                #pragma unroll
                for (int m = 0; m < 4; ++m)
                    #pragma unroll
                    for (int nf = 0; nf < 4; ++nf)
                        acc[m][nf] = __builtin_amdgcn_mfma_f32_16x16x32_bf16(
                            a[m], b[nf], acc[m][nf], 0, 0, 0);
            }
            __syncthreads();                // protect LDS before next stage
        }
    }

    // epilogue: o = o0 + wr*64 + m*16 + (lane>>4)*4 + r ; pos = p0 + wc*64 + nf*16 + (lane&15)
    #pragma unroll
    for (int m = 0; m < 4; ++m) {
        const int obase = o0 + wr * 64 + m * 16 + (lane >> 4) * 4;
        #pragma unroll
        for (int nf = 0; nf < 4; ++nf) {
            const int p = p0 + wc * 64 + nf * 16 + (lane & 15);
            if (p < 3136) {
                #pragma unroll
                for (int r = 0; r < 4; ++r)
                    out[((size_t)(n * 256 + obase + r)) * 3136 + p] = acc[m][nf][r];
            }
        }
    }
}

// ---------------------------------------------------------------------------
// Fallback: naive direct conv (only if ws_size too small). Correct but slow.
// ---------------------------------------------------------------------------
__global__ __launch_bounds__(256) void conv_naive_kernel(const float* __restrict__ x,
                                                         const float* __restrict__ w,
                                                         float* __restrict__ out) {
    const int n = blockIdx.z;
    const int o = blockIdx.y;
    const int strip = blockIdx.x;
    __shared__ float wqs[2304];
    __shared__ float red[4];
    __shared__ float s_scale;
    const float* wo = w + (size_t)o * 2304;
    float m = 0.f;
    for (int i = threadIdx.x; i < 2304; i += 256) m = fmaxf(m, fabsf(wo[i]));
    #pragma unroll
    for (int off = 32; off >= 1; off >>= 1) m = fmaxf(m, __shfl_down(m, off));
    if ((threadIdx.x & 63) == 0) red[threadIdx.x >> 6] = m;
    __syncthreads();
    if (threadIdx.x == 0) {
        float am = fmaxf(fmaxf(red[0], red[1]), fmaxf(red[2], red[3]));
        s_scale = fmaxf(am / QMAX, SCALE_MIN);
    }
    __syncthreads();
    const float scale = s_scale;
    for (int i = threadIdx.x; i < 2304; i += 256) {
        float q = rintf(wo[i] / scale);
        q = fminf(QMAX, fmaxf(-QMAX, q));
        wqs[i] = q * scale;
    }
    __syncthreads();
    int p = strip * 256 + threadIdx.x;
    if (p >= 3136) return;
    int h = p / 56, wcol = p - h * 56;
    float acc = 0.f;
    for (int c = 0; c < 256; ++c) {
        const float* xc = x + ((size_t)(n * 256 + c)) * 3136;
        const float* wk = wqs + c * 9;
        #pragma unroll
        for (int kh = 0; kh < 3; ++kh) {
            int hh = h + kh - 1;
            if (hh < 0 || hh > 55) continue;
            #pragma unroll
            for (int kw = 0; kw < 3; ++kw) {
                int ww2 = wcol + kw - 1;
                if (ww2 < 0 || ww2 > 55) continue;
                acc += xc[hh * 56 + ww2] * wk[kh * 3 + kw];
            }
        }
    }
    out[((size_t)(n * 256 + o)) * 3136 + p] = acc;
}

// ---------------------------------------------------------------------------
extern "C" void kernel_launch(void* const* d_in, const int* in_sizes, int n_in,
                              void* d_out, int out_size, void* d_ws, size_t ws_size,
                              hipStream_t stream) {
    const float* x = (const float*)d_in[0];
    const float* w = (const float*)d_in[1];
    float* out = (float*)d_out;

    const size_t WQ_BYTES   = 9ull * 256 * 256 * 2;            // 1,179,648
    const size_t XPAD_OFF   = WQ_BYTES;                        // 16B aligned
    const size_t XPAD_BYTES = 32ull * 58 * 58 * 256 * 2;       // 55,083,008

    if (ws_size >= XPAD_OFF + XPAD_BYTES) {
        __bf16* wq   = (__bf16*)d_ws;
        __bf16* xpad = (__bf16*)((char*)d_ws + XPAD_OFF);
        zero_halo_kernel<<<912, 256, 0, stream>>>(xpad);       // 233472 threads
        quant_w_kernel<<<256, 256, 0, stream>>>(w, wq);
        convert_x_kernel<<<dim3(98, 8, 32), 256, 0, stream>>>(x, xpad);
        conv_mfma_kernel<<<dim3(800, 2), 256, 0, stream>>>(xpad, wq, out);
    } else {
        conv_naive_kernel<<<dim3(13, 256, 32), 256, 0, stream>>>(x, w, out);
    }
}

// Round 3
// 185.496 us; speedup vs baseline: 1.4399x; 1.0341x over previous
//
#include <hip/hip_runtime.h>
#include <cstdint>
#include <cstddef>

typedef __bf16 bf16x8 __attribute__((ext_vector_type(8)));
typedef float  f32x4  __attribute__((ext_vector_type(4)));
typedef float  f32x16 __attribute__((ext_vector_type(16)));
typedef int    i32x4  __attribute__((ext_vector_type(4)));

#define QMAX 7.0f
#define SCALE_MIN 2e-16f

#define BAR()    asm volatile("s_barrier" ::: "memory")
#define WAITV0() asm volatile("s_waitcnt vmcnt(0)" ::: "memory")

// ---------------------------------------------------------------------------
// Kernel 1: per-output-channel fake-quant of w [256,256,3,3] -> bf16 wq[tap][o][c]
// ---------------------------------------------------------------------------
__global__ __launch_bounds__(256) void quant_w_kernel(const float* __restrict__ w,
                                                      __bf16* __restrict__ wq) {
    const int o = blockIdx.x;
    const int t = threadIdx.x;
    const float* wo = w + (size_t)o * 2304;

    float vals[9];
    float m = 0.f;
    #pragma unroll
    for (int i = 0; i < 9; ++i) {
        float v = wo[t + i * 256];
        vals[i] = v;
        m = fmaxf(m, fabsf(v));
    }
    #pragma unroll
    for (int off = 32; off >= 1; off >>= 1) m = fmaxf(m, __shfl_down(m, off));
    __shared__ float red[4];
    __shared__ float s_scale;
    if ((t & 63) == 0) red[t >> 6] = m;
    __syncthreads();
    if (t == 0) {
        float am = fmaxf(fmaxf(red[0], red[1]), fmaxf(red[2], red[3]));
        s_scale = fmaxf(am / QMAX, SCALE_MIN);
    }
    __syncthreads();
    const float scale = s_scale;

    #pragma unroll
    for (int i = 0; i < 9; ++i) {
        int idx = t + i * 256;           // = c*9 + tap
        int c = idx / 9;
        int tap = idx - c * 9;
        float q = rintf(vals[i] / scale);          // round-half-even, matches jnp.round
        q = fminf(QMAX, fmaxf(-QMAX, q));
        wq[(size_t)tap * 65536 + (size_t)o * 256 + c] = (__bf16)(q * scale);
    }
}

// ---------------------------------------------------------------------------
// Kernel 2: x NCHW fp32 [32,256,56,56] -> padded NHWC bf16 [32][58][58][256]
// ---------------------------------------------------------------------------
__global__ __launch_bounds__(256) void convert_x_kernel(const float* __restrict__ x,
                                                        __bf16* __restrict__ xpad) {
    __shared__ float tile[32][33];
    const int n  = blockIdx.z;
    const int c0 = blockIdx.y * 32;
    const int p0 = blockIdx.x * 32;
    const int tx = threadIdx.x & 31;
    const int ty = threadIdx.x >> 5;

    #pragma unroll
    for (int r = 0; r < 4; ++r) {
        int c = c0 + ty + r * 8;
        tile[ty + r * 8][tx] = x[((size_t)(n * 256 + c)) * 3136 + p0 + tx];
    }
    __syncthreads();
    #pragma unroll
    for (int r = 0; r < 4; ++r) {
        int p = p0 + ty + r * 8;
        int h = p / 56, wcol = p - h * 56;
        xpad[(((size_t)n * 58 + h + 1) * 58 + (wcol + 1)) * 256 + c0 + tx] =
            (__bf16)tile[tx][ty + r * 8];
    }
}

// ---------------------------------------------------------------------------
// Kernel 2b: zero the 1-cell halo of xpad.
// ---------------------------------------------------------------------------
__global__ __launch_bounds__(256) void zero_halo_kernel(__bf16* __restrict__ xpad) {
    const int t = blockIdx.x * 256 + threadIdx.x;
    const int cvec = t & 31;
    const int r    = t >> 5;
    const int n    = r / 228;
    const int pos  = r - n * 228;
    if (n >= 32) return;
    int h, wcol;
    if      (pos < 58)  { h = 0;          wcol = pos; }
    else if (pos < 116) { h = 57;         wcol = pos - 58; }
    else if (pos < 172) { h = pos - 115;  wcol = 0; }
    else                { h = pos - 171;  wcol = 57; }
    i32x4* dst = (i32x4*)(xpad + (((size_t)n * 58 + h) * 58 + wcol) * 256);
    dst[cvec] = (i32x4){0, 0, 0, 0};
}

// ---------------------------------------------------------------------------
// Kernel 3: implicit-GEMM conv, 8-phase-style schedule.
// Block: 256 o x 256 pos, 512 thr (8 waves, 2Mx4N), per-wave 128x64,
// mfma_f32_32x32x16_bf16, BK=64, K-steps = 9 taps x 4 c-chunks = 36.
// LDS 128 KiB: dbuf x (A 32K + B 32K). One vmcnt(0) per K-step, at the end,
// after the next step's 8 gloads have had 4 phases to land (counted effect).
// 16B-chunk XOR swizzle (proven 0-conflict in R2), pre-applied on the global
// source so the global_load_lds destination stays linear.
// ---------------------------------------------------------------------------
__device__ __forceinline__ void gload_lds16(const void* g, void* l) {
    __builtin_amdgcn_global_load_lds((const __attribute__((address_space(1))) void*)g,
                                     (__attribute__((address_space(3))) void*)l,
                                     16, 0, 0);
}

__global__ __launch_bounds__(512, 2) void conv_mfma_kernel(const __bf16* __restrict__ xpad,
                                                           const __bf16* __restrict__ wq,
                                                           float* __restrict__ out) {
    extern __shared__ __align__(16) char lds[];   // 131072 B
    const int tid  = threadIdx.x;
    const int wv   = tid >> 6;
    const int lane = tid & 63;
    const int bid  = blockIdx.x;
    const int swz  = (bid & 7) * 49 + (bid >> 3);   // 392 = 8*49 exact bijection
    const int p0   = swz * 256;

    const int wr = wv >> 2;        // 0..1 : o-half (128)
    const int wc = wv & 3;         // 0..3 : pos-quarter (64)

    // ---- staging setup: 8 issues/step of 512thr x 16B = 8KB (64 rows) each
    const int srow  = wv * 8 + (lane >> 3);          // row within 64-row issue
    const int schunk = (lane & 7) ^ (lane >> 3);     // pre-swizzled source chunk
    const __bf16* pAg = wq + (size_t)srow * 256 + schunk * 8;
    const __bf16* pB[4];
    #pragma unroll
    for (int p = 0; p < 4; ++p) {
        int pos = p0 + p * 64 + srow;                // < 100352 always (exact tiling)
        int ni = pos / 3136;
        int hw = pos - ni * 3136;
        int h = hw / 56, w = hw - h * 56;
        pB[p] = xpad + (((size_t)ni * 58 + h) * 58 + w) * 256 + schunk * 8;
    }

    // ---- fragment read setup (rows 128B wide; chunk ^= row&7 == lane&7) ----
    const int hi = lane >> 5;
    int kxo[4];
    #pragma unroll
    for (int ks = 0; ks < 4; ++ks)
        kxo[ks] = ((ks * 2 + hi) ^ (lane & 7)) * 16;
    const int arowb = (wr * 128 + (lane & 31)) * 128;
    const int browb = (wc * 64  + (lane & 31)) * 128;

    f32x16 acc[4][2];
    #pragma unroll
    for (int m = 0; m < 4; ++m)
        #pragma unroll
        for (int n = 0; n < 2; ++n)
            acc[m][n] = (f32x16)(0.f);

    // ---- prologue: stage K-step 0 (tap0, cc0) into buf0 ----
    {
        char* wa = lds;
        char* wb = lds + 32768;
        #pragma unroll
        for (int p = 0; p < 4; ++p) {
            gload_lds16(pAg + p * 16384, wa + (p * 64 + wv * 8) * 128);
            gload_lds16(pB[p],           wb + (p * 64 + wv * 8) * 128);
        }
        WAITV0();
        BAR();
    }

    for (int s = 0; s < 36; ++s) {
        const int cur = s & 1;
        const char* Ard = lds + (cur ? 65536 : 0);
        const char* Brd = Ard + 32768;
        char* Awr = lds + (cur ? 0 : 65536);
        char* Bwr = Awr + 32768;
        const bool stg = (s < 35);
        int aoffN = 0, boffN = 0;
        if (stg) {
            const int sn = s + 1;
            const int tapN = sn >> 2, ccN = sn & 3;
            const int khN = tapN / 3, kwN = tapN - khN * 3;
            aoffN = tapN * 65536 + ccN * 64;
            boffN = (khN * 58 + kwN) * 256 + ccN * 64;
        }

        bf16x8 a0[4], a1[4], b0[4], b1[4];

        // ---- phase 0: (m0,m1) x n0 ----
        if (stg) {
            gload_lds16(pAg + 0 * 16384 + aoffN, Awr + (0 * 64 + wv * 8) * 128);
            gload_lds16(pB[0] + boffN,           Bwr + (0 * 64 + wv * 8) * 128);
        }
        #pragma unroll
        for (int ks = 0; ks < 4; ++ks) {
            a0[ks] = *(const bf16x8*)(Ard + arowb + 0 * 4096 + kxo[ks]);
            a1[ks] = *(const bf16x8*)(Ard + arowb + 1 * 4096 + kxo[ks]);
            b0[ks] = *(const bf16x8*)(Brd + browb + 0 * 4096 + kxo[ks]);
        }
        BAR();
        __builtin_amdgcn_s_setprio(1);
        #pragma unroll
        for (int ks = 0; ks < 4; ++ks) {
            acc[0][0] = __builtin_amdgcn_mfma_f32_32x32x16_bf16(a0[ks], b0[ks], acc[0][0], 0, 0, 0);
            acc[1][0] = __builtin_amdgcn_mfma_f32_32x32x16_bf16(a1[ks], b0[ks], acc[1][0], 0, 0, 0);
        }
        __builtin_amdgcn_s_setprio(0);
        BAR();

        // ---- phase 1: (m0,m1) x n1 ----
        if (stg) {
            gload_lds16(pAg + 1 * 16384 + aoffN, Awr + (1 * 64 + wv * 8) * 128);
            gload_lds16(pB[1] + boffN,           Bwr + (1 * 64 + wv * 8) * 128);
        }
        #pragma unroll
        for (int ks = 0; ks < 4; ++ks)
            b1[ks] = *(const bf16x8*)(Brd + browb + 1 * 4096 + kxo[ks]);
        BAR();
        __builtin_amdgcn_s_setprio(1);
        #pragma unroll
        for (int ks = 0; ks < 4; ++ks) {
            acc[0][1] = __builtin_amdgcn_mfma_f32_32x32x16_bf16(a0[ks], b1[ks], acc[0][1], 0, 0, 0);
            acc[1][1] = __builtin_amdgcn_mfma_f32_32x32x16_bf16(a1[ks], b1[ks], acc[1][1], 0, 0, 0);
        }
        __builtin_amdgcn_s_setprio(0);
        BAR();

        // ---- phase 2: (m2,m3) x n0 ---- (reuse a0/a1 regs for m2/m3)
        if (stg) {
            gload_lds16(pAg + 2 * 16384 + aoffN, Awr + (2 * 64 + wv * 8) * 128);
            gload_lds16(pB[2] + boffN,           Bwr + (2 * 64 + wv * 8) * 128);
        }
        #pragma unroll
        for (int ks = 0; ks < 4; ++ks) {
            a0[ks] = *(const bf16x8*)(Ard + arowb + 2 * 4096 + kxo[ks]);
            a1[ks] = *(const bf16x8*)(Ard + arowb + 3 * 4096 + kxo[ks]);
        }
        BAR();
        __builtin_amdgcn_s_setprio(1);
        #pragma unroll
        for (int ks = 0; ks < 4; ++ks) {
            acc[2][0] = __builtin_amdgcn_mfma_f32_32x32x16_bf16(a0[ks], b0[ks], acc[2][0], 0, 0, 0);
            acc[3][0] = __builtin_amdgcn_mfma_f32_32x32x16_bf16(a1[ks], b0[ks], acc[3][0], 0, 0, 0);
        }
        __builtin_amdgcn_s_setprio(0);
        BAR();

        // ---- phase 3: (m2,m3) x n1 ---- (no new ds_reads)
        if (stg) {
            gload_lds16(pAg + 3 * 16384 + aoffN, Awr + (3 * 64 + wv * 8) * 128);
            gload_lds16(pB[3] + boffN,           Bwr + (3 * 64 + wv * 8) * 128);
        }
        BAR();
        __builtin_amdgcn_s_setprio(1);
        #pragma unroll
        for (int ks = 0; ks < 4; ++ks) {
            acc[2][1] = __builtin_amdgcn_mfma_f32_32x32x16_bf16(a0[ks], b1[ks], acc[2][1], 0, 0, 0);
            acc[3][1] = __builtin_amdgcn_mfma_f32_32x32x16_bf16(a1[ks], b1[ks], acc[3][1], 0, 0, 0);
        }
        __builtin_amdgcn_s_setprio(0);
        BAR();

        WAITV0();   // next step's 8 loads: had 4 phases (~2500cy) to land
        BAR();
    }

    // ---- epilogue: 32x32 C/D: col(pos)=lane&31, row(o)=(r&3)+8*(r>>2)+4*hi
    #pragma unroll
    for (int n = 0; n < 2; ++n) {
        const int pos = p0 + wc * 64 + n * 32 + (lane & 31);
        const int ni = pos / 3136;
        const int hw = pos - ni * 3136;
        float* ob = out + (size_t)ni * 802816 + hw;
        #pragma unroll
        for (int m = 0; m < 4; ++m) {
            const int om = wr * 128 + m * 32 + 4 * hi;
            #pragma unroll
            for (int r = 0; r < 16; ++r) {
                const int o = om + (r & 3) + 8 * (r >> 2);
                ob[(size_t)o * 3136] = acc[m][n][r];
            }
        }
    }
}

// ---------------------------------------------------------------------------
// Fallback: naive direct conv (only if ws_size too small).
// ---------------------------------------------------------------------------
__global__ __launch_bounds__(256) void conv_naive_kernel(const float* __restrict__ x,
                                                         const float* __restrict__ w,
                                                         float* __restrict__ out) {
    const int n = blockIdx.z;
    const int o = blockIdx.y;
    const int strip = blockIdx.x;
    __shared__ float wqs[2304];
    __shared__ float red[4];
    __shared__ float s_scale;
    const float* wo = w + (size_t)o * 2304;
    float m = 0.f;
    for (int i = threadIdx.x; i < 2304; i += 256) m = fmaxf(m, fabsf(wo[i]));
    #pragma unroll
    for (int off = 32; off >= 1; off >>= 1) m = fmaxf(m, __shfl_down(m, off));
    if ((threadIdx.x & 63) == 0) red[threadIdx.x >> 6] = m;
    __syncthreads();
    if (threadIdx.x == 0) {
        float am = fmaxf(fmaxf(red[0], red[1]), fmaxf(red[2], red[3]));
        s_scale = fmaxf(am / QMAX, SCALE_MIN);
    }
    __syncthreads();
    const float scale = s_scale;
    for (int i = threadIdx.x; i < 2304; i += 256) {
        float q = rintf(wo[i] / scale);
        q = fminf(QMAX, fmaxf(-QMAX, q));
        wqs[i] = q * scale;
    }
    __syncthreads();
    int p = strip * 256 + threadIdx.x;
    if (p >= 3136) return;
    int h = p / 56, wcol = p - h * 56;
    float acc = 0.f;
    for (int c = 0; c < 256; ++c) {
        const float* xc = x + ((size_t)(n * 256 + c)) * 3136;
        const float* wk = wqs + c * 9;
        #pragma unroll
        for (int kh = 0; kh < 3; ++kh) {
            int hh = h + kh - 1;
            if (hh < 0 || hh > 55) continue;
            #pragma unroll
            for (int kw = 0; kw < 3; ++kw) {
                int ww2 = wcol + kw - 1;
                if (ww2 < 0 || ww2 > 55) continue;
                acc += xc[hh * 56 + ww2] * wk[kh * 3 + kw];
            }
        }
    }
    out[((size_t)(n * 256 + o)) * 3136 + p] = acc;
}

// ---------------------------------------------------------------------------
extern "C" void kernel_launch(void* const* d_in, const int* in_sizes, int n_in,
                              void* d_out, int out_size, void* d_ws, size_t ws_size,
                              hipStream_t stream) {
    const float* x = (const float*)d_in[0];
    const float* w = (const float*)d_in[1];
    float* out = (float*)d_out;

    const size_t WQ_BYTES   = 9ull * 256 * 256 * 2;            // 1,179,648
    const size_t XPAD_OFF   = WQ_BYTES;
    const size_t XPAD_BYTES = 32ull * 58 * 58 * 256 * 2;       // 55,083,008

    if (ws_size >= XPAD_OFF + XPAD_BYTES) {
        __bf16* wq   = (__bf16*)d_ws;
        __bf16* xpad = (__bf16*)((char*)d_ws + XPAD_OFF);
        hipFuncSetAttribute((const void*)conv_mfma_kernel,
                            hipFuncAttributeMaxDynamicSharedMemorySize, 131072);
        zero_halo_kernel<<<912, 256, 0, stream>>>(xpad);
        quant_w_kernel<<<256, 256, 0, stream>>>(w, wq);
        convert_x_kernel<<<dim3(98, 8, 32), 256, 0, stream>>>(x, xpad);
        conv_mfma_kernel<<<392, 512, 131072, stream>>>(xpad, wq, out);
    } else {
        conv_naive_kernel<<<dim3(13, 256, 32), 256, 0, stream>>>(x, w, out);
    }
}

// Round 4
// 173.206 us; speedup vs baseline: 1.5421x; 1.0710x over previous
//
#include <hip/hip_runtime.h>
#include <cstdint>
#include <cstddef>

typedef __bf16 bf16x8 __attribute__((ext_vector_type(8)));
typedef float  f32x4  __attribute__((ext_vector_type(4)));
typedef float  f32x16 __attribute__((ext_vector_type(16)));
typedef int    i32x4  __attribute__((ext_vector_type(4)));

#define QMAX 7.0f
#define SCALE_MIN 2e-16f

#define BAR()     asm volatile("s_barrier" ::: "memory")
#define WAITVM(N) asm volatile("s_waitcnt vmcnt(" #N ")" ::: "memory")

// ---------------------------------------------------------------------------
// Kernel 1: per-output-channel fake-quant of w [256,256,3,3] -> bf16 wq[tap][o][c]
// ---------------------------------------------------------------------------
__global__ __launch_bounds__(256) void quant_w_kernel(const float* __restrict__ w,
                                                      __bf16* __restrict__ wq) {
    const int o = blockIdx.x;
    const int t = threadIdx.x;
    const float* wo = w + (size_t)o * 2304;

    float vals[9];
    float m = 0.f;
    #pragma unroll
    for (int i = 0; i < 9; ++i) {
        float v = wo[t + i * 256];
        vals[i] = v;
        m = fmaxf(m, fabsf(v));
    }
    #pragma unroll
    for (int off = 32; off >= 1; off >>= 1) m = fmaxf(m, __shfl_down(m, off));
    __shared__ float red[4];
    __shared__ float s_scale;
    if ((t & 63) == 0) red[t >> 6] = m;
    __syncthreads();
    if (t == 0) {
        float am = fmaxf(fmaxf(red[0], red[1]), fmaxf(red[2], red[3]));
        s_scale = fmaxf(am / QMAX, SCALE_MIN);
    }
    __syncthreads();
    const float scale = s_scale;

    #pragma unroll
    for (int i = 0; i < 9; ++i) {
        int idx = t + i * 256;           // = c*9 + tap
        int c = idx / 9;
        int tap = idx - c * 9;
        float q = rintf(vals[i] / scale);          // round-half-even, matches jnp.round
        q = fminf(QMAX, fmaxf(-QMAX, q));
        wq[(size_t)tap * 65536 + (size_t)o * 256 + c] = (__bf16)(q * scale);
    }
}

// ---------------------------------------------------------------------------
// Kernel 2: x NCHW fp32 [32,256,56,56] -> padded NHWC bf16 [32][58][58][256]
// ---------------------------------------------------------------------------
__global__ __launch_bounds__(256) void convert_x_kernel(const float* __restrict__ x,
                                                        __bf16* __restrict__ xpad) {
    __shared__ float tile[32][33];
    const int n  = blockIdx.z;
    const int c0 = blockIdx.y * 32;
    const int p0 = blockIdx.x * 32;
    const int tx = threadIdx.x & 31;
    const int ty = threadIdx.x >> 5;

    #pragma unroll
    for (int r = 0; r < 4; ++r) {
        int c = c0 + ty + r * 8;
        tile[ty + r * 8][tx] = x[((size_t)(n * 256 + c)) * 3136 + p0 + tx];
    }
    __syncthreads();
    #pragma unroll
    for (int r = 0; r < 4; ++r) {
        int p = p0 + ty + r * 8;
        int h = p / 56, wcol = p - h * 56;
        xpad[(((size_t)n * 58 + h + 1) * 58 + (wcol + 1)) * 256 + c0 + tx] =
            (__bf16)tile[tx][ty + r * 8];
    }
}

// ---------------------------------------------------------------------------
// Kernel 2b: zero the 1-cell halo of xpad.
// ---------------------------------------------------------------------------
__global__ __launch_bounds__(256) void zero_halo_kernel(__bf16* __restrict__ xpad) {
    const int t = blockIdx.x * 256 + threadIdx.x;
    const int cvec = t & 31;
    const int r    = t >> 5;
    const int n    = r / 228;
    const int pos  = r - n * 228;
    if (n >= 32) return;
    int h, wcol;
    if      (pos < 58)  { h = 0;          wcol = pos; }
    else if (pos < 116) { h = 57;         wcol = pos - 58; }
    else if (pos < 172) { h = pos - 115;  wcol = 0; }
    else                { h = pos - 171;  wcol = 57; }
    i32x4* dst = (i32x4*)(xpad + (((size_t)n * 58 + h) * 58 + wcol) * 256);
    dst[cvec] = (i32x4){0, 0, 0, 0};
}

// ---------------------------------------------------------------------------
// Kernel 3: implicit-GEMM conv, 4-phase schedule with COUNTED vmcnt (T4).
// Block: 256 o x 256 pos, 512 thr (8 waves, 2Mx4N), per-wave 128x64,
// mfma_f32_32x32x16_bf16, BK=64, 36 K-steps (9 taps x 4 c-chunks).
// LDS 128 KiB double-buffered. Issue->row mapping interleaved so each phase
// depends only on a FIFO PREFIX of the step's 8 gloads:
//   A-issue j -> rows {j*32..+31} u {128+j*32..+31}
//   B-issue j -> rows {q*64 + j*16..+15} for q=0..3
// Issue order per step (for s+1): ph0:[A0,B0,A1,B1] ph1:[B2,B3] ph2:[A2,A3].
// Waits: ph0 vmcnt(4), ph1 vmcnt(6), ph2 vmcnt(6)  (tail step: 4/2/0).
// No vmcnt(0) in the main loop. 16B-chunk XOR swizzle as in R2/R3 (content
// identical to R3; read addressing unchanged).
// ---------------------------------------------------------------------------
__device__ __forceinline__ void gload_lds16(const void* g, void* l) {
    __builtin_amdgcn_global_load_lds((const __attribute__((address_space(1))) void*)g,
                                     (__attribute__((address_space(3))) void*)l,
                                     16, 0, 0);
}

__global__ __launch_bounds__(512, 2) void conv_mfma_kernel(const __bf16* __restrict__ xpad,
                                                           const __bf16* __restrict__ wq,
                                                           float* __restrict__ out) {
    extern __shared__ __align__(16) char lds[];   // 131072 B
    const int tid  = threadIdx.x;
    const int wv   = tid >> 6;
    const int lane = tid & 63;
    const int bid  = blockIdx.x;
    const int swz  = (bid & 7) * 49 + (bid >> 3);   // 392 = 8*49 exact bijection
    const int p0   = swz * 256;

    const int wr = wv >> 2;        // 0..1 : o-half (128)
    const int wc = wv & 3;         // 0..3 : pos-quarter (64)

    // ---- staging row mappings (identity content: LDS row r <-> o / pos = r)
    const int schunk = (lane & 7) ^ (lane >> 3);     // pre-swizzled source chunk
    // A-issue j: wave wv covers rows (wv>>2)*128 + j*32 + (wv&3)*8 + (lane>>3)
    const int srowA = (wv >> 2) * 128 + (wv & 3) * 8 + (lane >> 3);
    const __bf16* pAg = wq + (size_t)srowA * 256 + schunk * 8;   // + j*32*256 per issue
    // B-issue j: wave wv covers rows (wv>>1)*64 + j*16 + (wv&1)*8 + (lane>>3)
    const int srowB = (wv >> 1) * 64 + (wv & 1) * 8 + (lane >> 3);
    const __bf16* pB[4];
    #pragma unroll
    for (int j = 0; j < 4; ++j) {
        int pos = p0 + srowB + j * 16;               // < 100352 (exact tiling)
        int ni = pos / 3136;
        int hw = pos - ni * 3136;
        int h = hw / 56, w = hw - h * 56;
        pB[j] = xpad + (((size_t)ni * 58 + h) * 58 + w) * 256 + schunk * 8;
    }
    // wave-uniform LDS dest bases (HW adds lane*16)
    const int adst = ((wv >> 2) * 128 + (wv & 3) * 8) * 128;   // + j*32*128 per issue
    const int bdst = ((wv >> 1) * 64  + (wv & 1) * 8) * 128;   // + j*16*128 per issue

    // ---- fragment read setup (rows 128B wide; stored chunk = c ^ (row&7)) --
    const int hi = lane >> 5;
    int kxo[4];
    #pragma unroll
    for (int ks = 0; ks < 4; ++ks)
        kxo[ks] = ((ks * 2 + hi) ^ (lane & 7)) * 16;
    const int arowb = (wr * 128 + (lane & 31)) * 128;
    const int browb = (wc * 64  + (lane & 31)) * 128;

    f32x16 acc[4][2];
    #pragma unroll
    for (int m = 0; m < 4; ++m)
        #pragma unroll
        for (int n = 0; n < 2; ++n)
            acc[m][n] = (f32x16)(0.f);

    // ---- prologue: stage K-step 0 into buf0, canonical FIFO order ----------
    {
        char* Aw = lds;
        char* Bw = lds + 32768;
        gload_lds16(pAg + 0 * 8192, Aw + adst + 0 * 4096);   // A0
        gload_lds16(pB[0],          Bw + bdst + 0 * 2048);   // B0
        gload_lds16(pAg + 1 * 8192, Aw + adst + 1 * 4096);   // A1
        gload_lds16(pB[1],          Bw + bdst + 1 * 2048);   // B1
        gload_lds16(pB[2],          Bw + bdst + 2 * 2048);   // B2
        gload_lds16(pB[3],          Bw + bdst + 3 * 2048);   // B3
        gload_lds16(pAg + 2 * 8192, Aw + adst + 2 * 4096);   // A2
        gload_lds16(pAg + 3 * 8192, Aw + adst + 3 * 4096);   // A3
    }

    for (int s = 0; s < 36; ++s) {
        const int cur = s & 1;
        const char* Ard = lds + (cur ? 65536 : 0);
        const char* Brd = Ard + 32768;
        char* Awr = lds + (cur ? 0 : 65536);
        char* Bwr = Awr + 32768;
        const bool stg = (s < 35);
        size_t aoffN = 0, boffN = 0;
        if (stg) {
            const int sn = s + 1;
            const int tapN = sn >> 2, ccN = sn & 3;
            const int khN = tapN / 3, kwN = tapN - khN * 3;
            aoffN = (size_t)tapN * 65536 + ccN * 64;
            boffN = (size_t)(khN * 58 + kwN) * 256 + ccN * 64;
        }

        bf16x8 a0[4], a1[4], b0[4], b1[4];

        // ==== phase 0: (m0,m1) x n0 — needs prefix 4 [A0,B0,A1,B1] ====
        WAITVM(4);
        BAR();
        #pragma unroll
        for (int ks = 0; ks < 4; ++ks) {
            a0[ks] = *(const bf16x8*)(Ard + arowb + 0 * 4096 + kxo[ks]);
            a1[ks] = *(const bf16x8*)(Ard + arowb + 1 * 4096 + kxo[ks]);
            b0[ks] = *(const bf16x8*)(Brd + browb + 0 * 4096 + kxo[ks]);
        }
        if (stg) {
            gload_lds16(pAg + 0 * 8192 + aoffN, Awr + adst + 0 * 4096);  // A0
            gload_lds16(pB[0] + boffN,          Bwr + bdst + 0 * 2048);  // B0
            gload_lds16(pAg + 1 * 8192 + aoffN, Awr + adst + 1 * 4096);  // A1
            gload_lds16(pB[1] + boffN,          Bwr + bdst + 1 * 2048);  // B1
        }
        __builtin_amdgcn_s_setprio(1);
        #pragma unroll
        for (int ks = 0; ks < 4; ++ks) {
            acc[0][0] = __builtin_amdgcn_mfma_f32_32x32x16_bf16(a0[ks], b0[ks], acc[0][0], 0, 0, 0);
            acc[1][0] = __builtin_amdgcn_mfma_f32_32x32x16_bf16(a1[ks], b0[ks], acc[1][0], 0, 0, 0);
        }
        __builtin_amdgcn_s_setprio(0);
        BAR();

        // ==== phase 1: (m0,m1) x n1 — needs prefix 6 [+B2,B3] ====
        if (stg) { WAITVM(6); } else { WAITVM(2); }
        BAR();
        #pragma unroll
        for (int ks = 0; ks < 4; ++ks)
            b1[ks] = *(const bf16x8*)(Brd + browb + 1 * 4096 + kxo[ks]);
        if (stg) {
            gload_lds16(pB[2] + boffN, Bwr + bdst + 2 * 2048);           // B2
            gload_lds16(pB[3] + boffN, Bwr + bdst + 3 * 2048);           // B3
        }
        __builtin_amdgcn_s_setprio(1);
        #pragma unroll
        for (int ks = 0; ks < 4; ++ks) {
            acc[0][1] = __builtin_amdgcn_mfma_f32_32x32x16_bf16(a0[ks], b1[ks], acc[0][1], 0, 0, 0);
            acc[1][1] = __builtin_amdgcn_mfma_f32_32x32x16_bf16(a1[ks], b1[ks], acc[1][1], 0, 0, 0);
        }
        __builtin_amdgcn_s_setprio(0);
        BAR();

        // ==== phase 2: (m2,m3) x n0 — needs prefix 8 [+A2,A3] ====
        if (stg) { WAITVM(6); } else { WAITVM(0); }
        BAR();
        #pragma unroll
        for (int ks = 0; ks < 4; ++ks) {
            a0[ks] = *(const bf16x8*)(Ard + arowb + 2 * 4096 + kxo[ks]);
            a1[ks] = *(const bf16x8*)(Ard + arowb + 3 * 4096 + kxo[ks]);
        }
        if (stg) {
            gload_lds16(pAg + 2 * 8192 + aoffN, Awr + adst + 2 * 4096);  // A2
            gload_lds16(pAg + 3 * 8192 + aoffN, Awr + adst + 3 * 4096);  // A3
        }
        __builtin_amdgcn_s_setprio(1);
        #pragma unroll
        for (int ks = 0; ks < 4; ++ks) {
            acc[2][0] = __builtin_amdgcn_mfma_f32_32x32x16_bf16(a0[ks], b0[ks], acc[2][0], 0, 0, 0);
            acc[3][0] = __builtin_amdgcn_mfma_f32_32x32x16_bf16(a1[ks], b0[ks], acc[3][0], 0, 0, 0);
        }
        __builtin_amdgcn_s_setprio(0);
        BAR();

        // ==== phase 3: (m2,m3) x n1 — no reads, no waits ====
        __builtin_amdgcn_s_setprio(1);
        #pragma unroll
        for (int ks = 0; ks < 4; ++ks) {
            acc[2][1] = __builtin_amdgcn_mfma_f32_32x32x16_bf16(a0[ks], b1[ks], acc[2][1], 0, 0, 0);
            acc[3][1] = __builtin_amdgcn_mfma_f32_32x32x16_bf16(a1[ks], b1[ks], acc[3][1], 0, 0, 0);
        }
        __builtin_amdgcn_s_setprio(0);
        BAR();
    }

    // ---- epilogue: 32x32 C/D: col(pos)=lane&31, row(o)=(r&3)+8*(r>>2)+4*hi
    #pragma unroll
    for (int n = 0; n < 2; ++n) {
        const int pos = p0 + wc * 64 + n * 32 + (lane & 31);
        const int ni = pos / 3136;
        const int hw = pos - ni * 3136;
        float* ob = out + (size_t)ni * 802816 + hw;
        #pragma unroll
        for (int m = 0; m < 4; ++m) {
            const int om = wr * 128 + m * 32 + 4 * hi;
            #pragma unroll
            for (int r = 0; r < 16; ++r) {
                const int o = om + (r & 3) + 8 * (r >> 2);
                ob[(size_t)o * 3136] = acc[m][n][r];
            }
        }
    }
}

// ---------------------------------------------------------------------------
// Fallback: naive direct conv (only if ws_size too small).
// ---------------------------------------------------------------------------
__global__ __launch_bounds__(256) void conv_naive_kernel(const float* __restrict__ x,
                                                         const float* __restrict__ w,
                                                         float* __restrict__ out) {
    const int n = blockIdx.z;
    const int o = blockIdx.y;
    const int strip = blockIdx.x;
    __shared__ float wqs[2304];
    __shared__ float red[4];
    __shared__ float s_scale;
    const float* wo = w + (size_t)o * 2304;
    float m = 0.f;
    for (int i = threadIdx.x; i < 2304; i += 256) m = fmaxf(m, fabsf(wo[i]));
    #pragma unroll
    for (int off = 32; off >= 1; off >>= 1) m = fmaxf(m, __shfl_down(m, off));
    if ((threadIdx.x & 63) == 0) red[threadIdx.x >> 6] = m;
    __syncthreads();
    if (threadIdx.x == 0) {
        float am = fmaxf(fmaxf(red[0], red[1]), fmaxf(red[2], red[3]));
        s_scale = fmaxf(am / QMAX, SCALE_MIN);
    }
    __syncthreads();
    const float scale = s_scale;
    for (int i = threadIdx.x; i < 2304; i += 256) {
        float q = rintf(wo[i] / scale);
        q = fminf(QMAX, fmaxf(-QMAX, q));
        wqs[i] = q * scale;
    }
    __syncthreads();
    int p = strip * 256 + threadIdx.x;
    if (p >= 3136) return;
    int h = p / 56, wcol = p - h * 56;
    float acc = 0.f;
    for (int c = 0; c < 256; ++c) {
        const float* xc = x + ((size_t)(n * 256 + c)) * 3136;
        const float* wk = wqs + c * 9;
        #pragma unroll
        for (int kh = 0; kh < 3; ++kh) {
            int hh = h + kh - 1;
            if (hh < 0 || hh > 55) continue;
            #pragma unroll
            for (int kw = 0; kw < 3; ++kw) {
                int ww2 = wcol + kw - 1;
                if (ww2 < 0 || ww2 > 55) continue;
                acc += xc[hh * 56 + ww2] * wk[kh * 3 + kw];
            }
        }
    }
    out[((size_t)(n * 256 + o)) * 3136 + p] = acc;
}

// ---------------------------------------------------------------------------
extern "C" void kernel_launch(void* const* d_in, const int* in_sizes, int n_in,
                              void* d_out, int out_size, void* d_ws, size_t ws_size,
                              hipStream_t stream) {
    const float* x = (const float*)d_in[0];
    const float* w = (const float*)d_in[1];
    float* out = (float*)d_out;

    const size_t WQ_BYTES   = 9ull * 256 * 256 * 2;            // 1,179,648
    const size_t XPAD_OFF   = WQ_BYTES;
    const size_t XPAD_BYTES = 32ull * 58 * 58 * 256 * 2;       // 55,083,008

    if (ws_size >= XPAD_OFF + XPAD_BYTES) {
        __bf16* wq   = (__bf16*)d_ws;
        __bf16* xpad = (__bf16*)((char*)d_ws + XPAD_OFF);
        hipFuncSetAttribute((const void*)conv_mfma_kernel,
                            hipFuncAttributeMaxDynamicSharedMemorySize, 131072);
        zero_halo_kernel<<<912, 256, 0, stream>>>(xpad);
        quant_w_kernel<<<256, 256, 0, stream>>>(w, wq);
        convert_x_kernel<<<dim3(98, 8, 32), 256, 0, stream>>>(x, xpad);
        conv_mfma_kernel<<<392, 512, 131072, stream>>>(xpad, wq, out);
    } else {
        conv_naive_kernel<<<dim3(13, 256, 32), 256, 0, stream>>>(x, w, out);
    }
}